// Round 8
// baseline (323.264 us; speedup 1.0000x reference)
//
#include <hip/hip_runtime.h>

typedef _Float16 f16;
typedef _Float16 f16x4 __attribute__((ext_vector_type(4)));
typedef _Float16 f16x8 __attribute__((ext_vector_type(8)));
typedef float f32x4 __attribute__((ext_vector_type(4)));

// ws layout
#define WS_QKW   0                       // [8b][8e][256c] f16 = 32 KiB
#define WS_MTP   32768                   // [256kc][256o][8] f16 = 1 MiB
#define WS_FLAGS (32768 + 1048576)       // flags[0]=qkw posts, flags[1]=mtp posts

// A[px][k]: 32 px rows x 2048 f16 (4096 B per row). 16-B chunks XOR-swizzled
// by px (4 bits): byte = px*4096 + ((k>>3)^(px&15))*16 + (k&7)*2.
static __device__ inline char* a_addr(char* Abase, int px, int k) {
    return Abase + px * 4096 + ((((k >> 3) ^ (px & 15)) << 4) | ((k & 7) << 1));
}

// ---------------------------------------------------------------------------
// k_fused: grid 256 x 1024, 1 block/CU (all co-resident).
// waves 4..15: stream c-tile -> A (4 barrier-paced quarters) + sumsq.
// waves 0..3:  one M-subtile per block (mtp slice); blocks 0..63 additionally
//              run the R0 query chain (qe->x1->qh->qkw), its stages aligned
//              with the load quarters -> setup hides under the c-load.
// qkw/mtp published via device-scope release/acquire flags (R5-proven).
// Then: dots MFMA -> attn-compute -> blend -> GEMM (R7 code).
// ---------------------------------------------------------------------------
__launch_bounds__(1024, 4)
__global__ void k_fused(const int* __restrict__ q, const float* __restrict__ emb,
                        const float* __restrict__ w1, const float* __restrict__ b1,
                        const float* __restrict__ w2, const float* __restrict__ b2,
                        const float* __restrict__ w_kv, const float* __restrict__ w_out,
                        const float* __restrict__ rms_w, const float* __restrict__ cin,
                        const float* __restrict__ b_out,
                        f16* __restrict__ qkw, f16* __restrict__ mtp,
                        int* __restrict__ flags, float* __restrict__ out) {
    int blk = blockIdx.x;
    int b = blk & 7;
    int hw0 = (blk >> 3) * 32;
    int t = threadIdx.x;
    int lane = t & 63, w = t >> 6;        // w 0..15
    int m16 = lane & 15, quad = lane >> 4;
    int half = lane >> 5;

    __shared__ char A[32 * 4096];               // 131072 B swizzled f16 [32px][2048k]
    __shared__ __align__(16) char poolA[8192];  // chain/M scratch, then dotsP
    __shared__ float wredS[16][16];             // [chunk c=(pxh<<3)|n][m16] sumsq
    __shared__ __align__(16) f16 attnH[2048];   // [e][px][n]

    float (*dotsP)[8][32] = (float (*)[8][32])poolA;   // [n][e][px] (post-chain)
    float* wvF  = (float*)poolA;                // [64][8]  (M stage)
    float* qeF  = (float*)(poolA + 2048);       // [256]
    float* x1LF = (float*)(poolA + 3072);       // [512]
    float* psF  = (float*)(poolA + 5120);       // [4][64]
    float* qhLF = (float*)(poolA + 6144);       // [64]

    // setup-role mappings
    bool chainblk = (blk < 64);
    int bq = blk >> 3, eq = blk & 7;            // query chain (blocks 0..63)
    int em = blk >> 5, c0m = (blk & 31) * 8;    // M-subtile (all 256 blocks)

    // load-role mapping: waves 4..15 cover 16 chunks (pxh,n); waves 4..7 take 2
    int lw = w - 4;                             // 0..11 for load waves
    int c1 = lw, c2 = 12 + lw;                  // c2 valid iff lw<4
    float ss1 = 0.f, ss2 = 0.f;

#define LOADP(c, p, ss)                                                         \
    {                                                                           \
        int pxh_ = (c) >> 3, n_ = (c) & 7;                                      \
        int px_ = pxh_ * 16 + m16;                                              \
        const float* cb0_ = cin + (((size_t)b) << 21) + hw0 + px_;              \
        int chb_ = n_ * 256 + quad * 64 + (p) * 16;                             \
        float v_[16];                                                           \
        _Pragma("unroll")                                                       \
        for (int j = 0; j < 16; ++j) v_[j] = cb0_[(size_t)(chb_ + j) << 10];    \
        f16x8 h0_, h1_;                                                         \
        _Pragma("unroll")                                                       \
        for (int j = 0; j < 8; ++j) { ss += v_[j] * v_[j]; h0_[j] = (f16)v_[j]; } \
        _Pragma("unroll")                                                       \
        for (int j = 0; j < 8; ++j) { float x_ = v_[8 + j]; ss += x_ * x_; h1_[j] = (f16)x_; } \
        *(f16x8*)a_addr(A, px_, chb_)     = h0_;                                \
        *(f16x8*)a_addr(A, px_, chb_ + 8) = h1_;                                \
    }

    // ---- region 0: M stage wv + chain qe load | load quarter 0 ----
    if (w < 4) {
        int d = t & 63, cc = t >> 6;
        wvF[d * 8 + cc]     = w_kv[(size_t)(c0m + cc) * 1024 + em * 128 + 64 + d];
        wvF[d * 8 + cc + 4] = w_kv[(size_t)(c0m + cc + 4) * 1024 + em * 128 + 64 + d];
        if (chainblk) qeF[t] = emb[(size_t)q[bq] * 256 + t];
    } else {
        LOADP(c1, 0, ss1);
        if (lw < 4) LOADP(c2, 0, ss2);
    }
    __syncthreads();

    // ---- region 1: M compute -> mtp | load quarter 1 ----
    if (w < 4) {
        int o = t;
        float acc[8];
#pragma unroll
        for (int c = 0; c < 8; ++c) acc[c] = 0.f;
#pragma unroll 4
        for (int d = 0; d < 64; ++d) {
            float wo = w_out[(size_t)(em * 64 + d) * 256 + o];
            float4 wa = *(const float4*)&wvF[d * 8];
            float4 wb = *(const float4*)&wvF[d * 8 + 4];
            acc[0] += wa.x * wo; acc[1] += wa.y * wo; acc[2] += wa.z * wo; acc[3] += wa.w * wo;
            acc[4] += wb.x * wo; acc[5] += wb.y * wo; acc[6] += wb.z * wo; acc[7] += wb.w * wo;
        }
        f16x8 ov;
#pragma unroll
        for (int c = 0; c < 8; ++c) ov[c] = (f16)(acc[c] * rms_w[c0m + c]);
        *(f16x8*)(mtp + ((size_t)((em * 256 + c0m) >> 3) * 256 + o) * 8) = ov;
        __threadfence();
    } else {
        LOADP(c1, 1, ss1);
        if (lw < 4) LOADP(c2, 1, ss2);
    }
    __syncthreads();

    // ---- region 2: post mtp; chain x1 = silu(qe@w1+b1) | load quarter 2 ----
    if (t == 0)
        __hip_atomic_fetch_add(&flags[1], 1, __ATOMIC_RELEASE, __HIP_MEMORY_SCOPE_AGENT);
    if (w < 4) {
        if (chainblk) {
            float a0 = b1[t], a1 = b1[t + 256];
#pragma unroll 4
            for (int c = 0; c < 256; ++c) {
                float qv = qeF[c];
                a0 += qv * w1[c * 512 + t];
                a1 += qv * w1[c * 512 + t + 256];
            }
            x1LF[t]       = a0 / (1.f + __expf(-a0));
            x1LF[t + 256] = a1 / (1.f + __expf(-a1));
        }
    } else {
        LOADP(c1, 2, ss1);
        if (lw < 4) LOADP(c2, 2, ss2);
    }
    __syncthreads();

    // ---- region 3: chain ps = x1 @ w2 slice | load quarter 3 ----
    if (w < 4) {
        if (chainblk) {
            int d = t & 63, ks = t >> 6;
            float acc = 0.f;
#pragma unroll 4
            for (int k = ks * 128; k < ks * 128 + 128; ++k)
                acc += x1LF[k] * w2[k * 512 + eq * 64 + d];
            psF[ks * 64 + d] = acc;
        }
    } else {
        LOADP(c1, 3, ss1);
        if (lw < 4) LOADP(c2, 3, ss2);
    }
    __syncthreads();

    // ---- region 4: chain qh reduce | wredS stores ----
    if (w >= 4) {
        ss1 += __shfl_xor(ss1, 16);
        ss1 += __shfl_xor(ss1, 32);
        if (lane < 16) wredS[c1][m16] = ss1;
        if (lw < 4) {
            ss2 += __shfl_xor(ss2, 16);
            ss2 += __shfl_xor(ss2, 32);
            if (lane < 16) wredS[c2][m16] = ss2;
        }
    } else if (chainblk && t < 64) {
        qhLF[t] = b2[eq * 64 + t] + psF[t] + psF[64 + t] + psF[128 + t] + psF[192 + t];
    }
    __syncthreads();

    // ---- region 5: chain qkw row = (qh . w_kv K-half) * rms_w ----
    if (chainblk && w < 4) {
        const float* row = w_kv + (size_t)t * 1024 + eq * 128;
        float a2 = 0.f;
#pragma unroll
        for (int dd = 0; dd < 64; dd += 4) {
            float4 wv4 = *(const float4*)(row + dd);
            a2 += qhLF[dd] * wv4.x + qhLF[dd + 1] * wv4.y
                + qhLF[dd + 2] * wv4.z + qhLF[dd + 3] * wv4.w;
        }
        qkw[(bq * 8 + eq) * 256 + t] = (f16)(a2 * rms_w[t]);
        __threadfence();
    }
    __syncthreads();

    // ---- region 6: post qkw (chain blocks); wait for qkw==64 && mtp==256 ----
    if (chainblk && t == 0)
        __hip_atomic_fetch_add(&flags[0], 1, __ATOMIC_RELEASE, __HIP_MEMORY_SCOPE_AGENT);
    if (t == 0) {
        while (__hip_atomic_load(&flags[0], __ATOMIC_ACQUIRE, __HIP_MEMORY_SCOPE_AGENT) < 64 ||
               __hip_atomic_load(&flags[1], __ATOMIC_ACQUIRE, __HIP_MEMORY_SCOPE_AGENT) < 256)
            __builtin_amdgcn_s_sleep(2);
    }
    __syncthreads();

    // ---- dots via MFMA: wave w -> n=w&7, px-half=w>>3 ----
    {
        int n = w & 7, pxh = w >> 3;
        f32x4 d0 = {0.f, 0.f, 0.f, 0.f};
        const f16* qrow = qkw + (size_t)b * 2048 + (m16 & 7) * 256;
#pragma unroll
        for (int ks = 0; ks < 8; ++ks) {
            f16x8 a0 = *(const f16x8*)a_addr(A, pxh * 16 + m16, n * 256 + ks * 32 + quad * 8);
            f16x8 bfr = *(const f16x8*)(qrow + ks * 32 + quad * 8);
            d0 = __builtin_amdgcn_mfma_f32_16x16x32_f16(a0, bfr, d0, 0, 0, 0);
        }
        if (m16 < 8) {   // D: col=m16=e, row=quad*4+r
#pragma unroll
            for (int r = 0; r < 4; ++r) dotsP[n][m16][pxh * 16 + quad * 4 + r] = d0[r];
        }
    }
    __syncthreads();

    // ---- pb preload (in flight across attn) + attn-compute ----
    int o = w * 16 + m16;
    f16x8 pb[8];
#pragma unroll
    for (int ks = 0; ks < 8; ++ks)
        pb[ks] = *(const f16x8*)(mtp + ((size_t)(ks * 4 + quad) * 256 + o) * 8);

    if (t < 256) {        // one softmax per (px,e); rinv per (px,n)
        int e = t >> 5, p = t & 31;
        int ph = p >> 4, pl = p & 15;
        float rv[8], l[8];
#pragma unroll
        for (int nn = 0; nn < 8; ++nn)
            rv[nn] = rsqrtf(wredS[(ph << 3) | nn][pl] * (1.f / 256.f) + 1e-6f);
#pragma unroll
        for (int nn = 0; nn < 8; ++nn) l[nn] = dotsP[nn][e][p] * rv[nn] * 0.125f;
        float mx = l[0];
#pragma unroll
        for (int nn = 1; nn < 8; ++nn) mx = fmaxf(mx, l[nn]);
        float s = 0.f;
#pragma unroll
        for (int nn = 0; nn < 8; ++nn) { l[nn] = __expf(l[nn] - mx); s += l[nn]; }
        float inv = 1.f / s;
        f16x8 av;
#pragma unroll
        for (int nn = 0; nn < 8; ++nn) av[nn] = (f16)(l[nn] * inv * rv[nn]);
        *(f16x8*)(attnH + e * 256 + p * 8) = av;
    }
    __syncthreads();

    // ---- blend (in place over A) ----
    {
        int bpx = lane & 31;
        int c0 = (w + half * 16) * 8;     // halves 16 windows apart -> 2-way
        f16x8 cv[8];
#pragma unroll
        for (int nn = 0; nn < 8; ++nn)
            cv[nn] = *(const f16x8*)a_addr(A, bpx, nn * 256 + c0);
#pragma unroll
        for (int e = 0; e < 8; ++e) {
            f16x8 av = *(const f16x8*)(attnH + e * 256 + bpx * 8);
            f16x8 r = {};
#pragma unroll
            for (int nn = 0; nn < 8; ++nn) {
                f16 an = av[nn];
#pragma unroll
                for (int j = 0; j < 8; ++j) r[j] += cv[nn][j] * an;   // v_pk_fma_f16
            }
            *(f16x8*)a_addr(A, bpx, e * 256 + c0) = r;
        }
    }
    __syncthreads();

    // ---- GEMM: out[32p][256o] = A[32][2048] @ M (wave w -> o 16-slice) ----
    {
        f32x4 acc0 = {0.f, 0.f, 0.f, 0.f};
        f32x4 acc1 = {0.f, 0.f, 0.f, 0.f};
#pragma unroll
        for (int ks = 0; ks < 8; ++ks) {   // preloaded B
            int k = ks * 32 + quad * 8;
            f16x8 af0 = *(const f16x8*)a_addr(A, m16, k);
            f16x8 af1 = *(const f16x8*)a_addr(A, m16 + 16, k);
            acc0 = __builtin_amdgcn_mfma_f32_16x16x32_f16(af0, pb[ks], acc0, 0, 0, 0);
            acc1 = __builtin_amdgcn_mfma_f32_16x16x32_f16(af1, pb[ks], acc1, 0, 0, 0);
        }
#pragma unroll 8
        for (int ks = 8; ks < 64; ++ks) {
            int k = (ks >> 3) * 256 + (ks & 7) * 32 + quad * 8;
            int kchunk = k >> 3;
            f16x8 bfr = *(const f16x8*)(mtp + ((size_t)kchunk * 256 + o) * 8);
            f16x8 af0 = *(const f16x8*)a_addr(A, m16, k);
            f16x8 af1 = *(const f16x8*)a_addr(A, m16 + 16, k);
            acc0 = __builtin_amdgcn_mfma_f32_16x16x32_f16(af0, bfr, acc0, 0, 0, 0);
            acc1 = __builtin_amdgcn_mfma_f32_16x16x32_f16(af1, bfr, acc1, 0, 0, 0);
        }
        float bo = b_out[o];
        float* drow = out + ((size_t)b * 256 + o) * 1024 + hw0;
        float4 v0 = {acc0[0] + bo, acc0[1] + bo, acc0[2] + bo, acc0[3] + bo};
        float4 v1 = {acc1[0] + bo, acc1[1] + bo, acc1[2] + bo, acc1[3] + bo};
        *(float4*)(drow + quad * 4)      = v0;   // px 0..15 half
        *(float4*)(drow + 16 + quad * 4) = v1;   // px 16..31 half
    }
#undef LOADP
}

extern "C" void kernel_launch(void* const* d_in, const int* in_sizes, int n_in,
                              void* d_out, int out_size, void* d_ws, size_t ws_size,
                              hipStream_t stream) {
    (void)in_sizes; (void)n_in; (void)out_size; (void)ws_size;
    const int*   q     = (const int*)d_in[0];
    const float* c     = (const float*)d_in[1];
    const float* rms_w = (const float*)d_in[2];
    const float* emb   = (const float*)d_in[3];
    const float* w1    = (const float*)d_in[4];
    const float* b1    = (const float*)d_in[5];
    const float* w2    = (const float*)d_in[6];
    const float* b2    = (const float*)d_in[7];
    const float* w_kv  = (const float*)d_in[8];
    const float* w_out = (const float*)d_in[9];
    const float* b_out = (const float*)d_in[10];
    float* out = (float*)d_out;

    char* ws = (char*)d_ws;
    f16* qkw   = (f16*)(ws + WS_QKW);
    f16* mtp   = (f16*)(ws + WS_MTP);
    int* flags = (int*)(ws + WS_FLAGS);

    hipMemsetAsync(flags, 0, 64, stream);   // reset post counters each iteration
    k_fused<<<256, 1024, 0, stream>>>(q, emb, w1, b1, w2, b2, w_kv, w_out, rms_w,
                                      c, b_out, qkw, mtp, flags, out);
}